// Round 24
// baseline (292.901 us; speedup 1.0000x reference)
//
#include <hip/hip_runtime.h>
#include <hip/hip_bf16.h>

#define BB 16
#define NN 512
#define DD 64
#define BN_ROWS (BB * NN)   // 8192

typedef unsigned short ushort;
typedef unsigned int uint;
typedef short bf16x8 __attribute__((ext_vector_type(8)));   // 8 bf16 = 4 VGPRs
typedef float f32x4  __attribute__((ext_vector_type(4)));   // MFMA acc

// ws layout: stats[128] | wpf fp32 frag-ordered [4096] | xbf bf16 frag-ordered [524288]
// Identities: Wp·(xi⊙xj) = (Wp⊙xi)·xj ; agg = (Σ e_j·x_j)/(Σ e_j), fused pass.
// NEW: one block = TWO rows (i0,i1) sharing every B-frag load; per-i A-frags
// built once per block into LDS (dedupes the 8x per-wave rebuild, frees VGPRs).

__device__ __forceinline__ uint pkbf2(float lo, float hi) {
    union { float f; uint u; } a, b; a.f = lo; b.f = hi;
    return __builtin_amdgcn_perm(b.u + 0x8000u, a.u + 0x8000u, 0x07060302u);
}
__device__ __forceinline__ float bflo(uint u) {
    union { uint i; float f; } c; c.i = u << 16; return c.f;
}
__device__ __forceinline__ float bfhi(uint u) {
    union { uint i; float f; } c; c.i = u & 0xffff0000u; return c.f;
}
__device__ __forceinline__ ushort f2bf_rne(float f) {
    union { float fl; uint u; } c; c.fl = f;
    return (ushort)((c.u + 0x7fffu + ((c.u >> 16) & 1u)) >> 16);
}

// no clamp: e=inf -> rcp=0 -> 1 (correct limit); e=0 -> -1 (correct)
__device__ __forceinline__ float fast_tanh(float x) {
    const float e = __builtin_amdgcn_exp2f(x * 2.885390081777927f); // 2x*log2(e)
    return 1.0f - 2.0f * __builtin_amdgcn_rcpf(e + 1.0f);
}

// One-time: x -> bf16 B-frag order; Wp -> fp32 A-frag order; zero stats.
__global__ __launch_bounds__(256) void prep_kernel(
    const float* __restrict__ x, const float* __restrict__ Wp,
    float* __restrict__ wpf, ushort* __restrict__ xbf, float* __restrict__ stats)
{
    const int tid = blockIdx.x * 256 + threadIdx.x;     // grid 256 -> 0..65535
    const int b = tid >> 12, rem = tid & 4095;
    const int jt = rem >> 7, ks = (rem >> 6) & 1, lane = rem & 63;
    const int qd = lane >> 4, ln = lane & 15;
    const float* __restrict__ src =
        x + ((size_t)(b * NN + jt * 16 + ln)) * DD + ks * 32 + qd * 8;
    const float4 v0 = *(const float4*)src;
    const float4 v1 = *(const float4*)(src + 4);
    uint4 o;
    o.x = pkbf2(v0.x, v0.y); o.y = pkbf2(v0.z, v0.w);
    o.z = pkbf2(v1.x, v1.y); o.w = pkbf2(v1.z, v1.w);
    ((uint4*)xbf)[tid] = o;                              // coalesced
    if (tid < DD * DD) {
        const int oo = tid >> 6, d = tid & 63;
        const int mt = oo >> 4, l2 = oo & 15;
        const int k2 = d >> 5, q2 = (d >> 3) & 3, e = d & 7;
        wpf[(((mt * 2 + k2) * 64) + (q2 * 16 + l2)) * 8 + e] = Wp[tid];
    }
    if (tid < 128) stats[tid] = 0.0f;
}

// Block (512 thr, 8 waves) per row-PAIR (b, i0=2m, i1=2m+1); wave wv owns
// j-tiles wv*4..wv*4+3 for BOTH rows, sharing B-frag loads.
__global__ __launch_bounds__(512, 2) void attn_kernel(
    const float* __restrict__ x,  const float* __restrict__ wpf,
    const ushort* __restrict__ xbf,
    const float* __restrict__ bp, const float* __restrict__ aw,
    const float* __restrict__ W1, const float* __restrict__ b1,
    const float* __restrict__ W2, const float* __restrict__ b2,
    float* __restrict__ out, float* __restrict__ stats)
{
    __shared__ __align__(16) ushort sWf[2][DD * DD];    // 16 KB: Wp⊙xi bf16, frag order
    __shared__ float part[2][8][DD];                    // 4 KB (reused twice)
    __shared__ __align__(16) float s_xi[2][DD], s_agg[2][DD], s_bp[DD], s_aw[DD];
    __shared__ float s_esum[2][8];

    const int t = threadIdx.x;                      // 0..511
    const int wv = t >> 6, lane = t & 63;
    const int blk = blockIdx.x;                     // 0..4095
    const int b = blk >> 8;                         // 256 pairs per b
    const int i0 = (blk & 255) * 2;
    const int qd = lane >> 4, ln = lane & 15;
    const ushort* __restrict__ xb16 = xbf + (size_t)b * (NN * DD);

    if (t < DD) {
        s_bp[t] = bp[t];
        s_aw[t] = aw[t];
        s_xi[0][t] = x[((size_t)(b * NN + i0)) * DD + t];
        s_xi[1][t] = x[((size_t)(b * NN + i0 + 1)) * DD + t];
    }
    __syncthreads();

    // build sWf[ii][f] = bf16(wpf[f] * xi[d(f)]) once per block, cooperatively
    #pragma unroll
    for (int ii = 0; ii < 2; ++ii)
        #pragma unroll
        for (int r = 0; r < 8; ++r) {
            const int f = r * 512 + t;              // 4096 elements
            const int g = f >> 9, l = (f >> 3) & 63, e = f & 7;
            const int d = (g & 1) * 32 + (l >> 4) * 8 + e;
            sWf[ii][f] = f2bf_rne(wpf[f] * s_xi[ii][d]);
        }
    __syncthreads();

    // ---- FUSED score + aggregate: 4 j-tiles, both rows, shared B loads ----
    float vacc0[16], vacc1[16];
    #pragma unroll
    for (int k = 0; k < 16; ++k) { vacc0[k] = 0.0f; vacc1[k] = 0.0f; }
    float esum0 = 0.0f, esum1 = 0.0f;

    #pragma unroll
    for (int tt = 0; tt < 4; ++tt) {
        const int tile = wv * 4 + tt;
        union { bf16x8 v; uint4 u; } b0, b1v;
        b0.v  = *(const bf16x8*)(xb16 + ((tile * 2 + 0) * 64 + lane) * 8);
        b1v.v = *(const bf16x8*)(xb16 + ((tile * 2 + 1) * 64 + lane) * 8);

        float p0 = 0, p1 = 0, p2 = 0, p3 = 0;      // row i0 partials
        float r0 = 0, r1 = 0, r2 = 0, r3 = 0;      // row i1 partials
        #pragma unroll
        for (int mt = 0; mt < 4; ++mt) {
            const float4 bp4 = *(const float4*)(s_bp + mt * 16 + qd * 4);
            const float4 aw4 = *(const float4*)(s_aw + mt * 16 + qd * 4);
            const bf16x8 a00 = *(const bf16x8*)(&sWf[0][((mt * 2 + 0) * 64 + lane) * 8]);
            const bf16x8 a01 = *(const bf16x8*)(&sWf[0][((mt * 2 + 1) * 64 + lane) * 8]);
            const bf16x8 a10 = *(const bf16x8*)(&sWf[1][((mt * 2 + 0) * 64 + lane) * 8]);
            const bf16x8 a11 = *(const bf16x8*)(&sWf[1][((mt * 2 + 1) * 64 + lane) * 8]);
            f32x4 acc0 = { bp4.x, bp4.y, bp4.z, bp4.w };
            f32x4 acc1 = acc0;
            acc0 = __builtin_amdgcn_mfma_f32_16x16x32_bf16(a00, b0.v,  acc0, 0, 0, 0);
            acc1 = __builtin_amdgcn_mfma_f32_16x16x32_bf16(a10, b0.v,  acc1, 0, 0, 0);
            acc0 = __builtin_amdgcn_mfma_f32_16x16x32_bf16(a01, b1v.v, acc0, 0, 0, 0);
            acc1 = __builtin_amdgcn_mfma_f32_16x16x32_bf16(a11, b1v.v, acc1, 0, 0, 0);
            p0 = fmaf(aw4.x, fast_tanh(acc0[0]), p0);
            r0 = fmaf(aw4.x, fast_tanh(acc1[0]), r0);
            p1 = fmaf(aw4.y, fast_tanh(acc0[1]), p1);
            r1 = fmaf(aw4.y, fast_tanh(acc1[1]), r1);
            p2 = fmaf(aw4.z, fast_tanh(acc0[2]), p2);
            r2 = fmaf(aw4.z, fast_tanh(acc1[2]), r2);
            p3 = fmaf(aw4.w, fast_tanh(acc0[3]), p3);
            r3 = fmaf(aw4.w, fast_tanh(acc1[3]), r3);
        }
        float sj0 = (p0 + p1) + (p2 + p3);
        float sj1 = (r0 + r1) + (r2 + r3);
        sj0 += __shfl_xor(sj0, 16);  sj1 += __shfl_xor(sj1, 16);
        sj0 += __shfl_xor(sj0, 32);  sj1 += __shfl_xor(sj1, 32);

        const float e0 = __builtin_amdgcn_exp2f(sj0 * 1.4426950408889634f);
        const float e1 = __builtin_amdgcn_exp2f(sj1 * 1.4426950408889634f);
        esum0 += e0;
        esum1 += e1;
        const float xd[16] = {
            bflo(b0.u.x),  bfhi(b0.u.x),  bflo(b0.u.y),  bfhi(b0.u.y),
            bflo(b0.u.z),  bfhi(b0.u.z),  bflo(b0.u.w),  bfhi(b0.u.w),
            bflo(b1v.u.x), bfhi(b1v.u.x), bflo(b1v.u.y), bfhi(b1v.u.y),
            bflo(b1v.u.z), bfhi(b1v.u.z), bflo(b1v.u.w), bfhi(b1v.u.w) };
        #pragma unroll
        for (int k = 0; k < 16; ++k) {
            vacc0[k] = fmaf(e0, xd[k], vacc0[k]);
            vacc1[k] = fmaf(e1, xd[k], vacc1[k]);
        }
    }

    // reduce over ln (j bits) within wave
    #pragma unroll
    for (int off = 1; off < 16; off <<= 1) {
        esum0 += __shfl_xor(esum0, off);
        esum1 += __shfl_xor(esum1, off);
        #pragma unroll
        for (int k = 0; k < 16; ++k) {
            vacc0[k] += __shfl_xor(vacc0[k], off);
            vacc1[k] += __shfl_xor(vacc1[k], off);
        }
    }
    if (lane == 0) { s_esum[0][wv] = esum0; s_esum[1][wv] = esum1; }
    if (ln == 0) {
        #pragma unroll
        for (int k = 0; k < 16; ++k) {
            const int d = (k >> 3) * 32 + qd * 8 + (k & 7);
            part[0][wv][d] = vacc0[k];
            part[1][wv][d] = vacc1[k];
        }
    }
    __syncthreads();

    // block combine: agg[ii][d]
    if (t < 128) {
        const int ii = t >> 6, d = t & 63;
        const float tot = ((s_esum[ii][0] + s_esum[ii][1]) + (s_esum[ii][2] + s_esum[ii][3]))
                        + ((s_esum[ii][4] + s_esum[ii][5]) + (s_esum[ii][6] + s_esum[ii][7]));
        const float a = ((part[ii][0][d] + part[ii][1][d]) + (part[ii][2][d] + part[ii][3][d]))
                      + ((part[ii][4][d] + part[ii][5][d]) + (part[ii][6][d] + part[ii][7][d]));
        s_agg[ii][d] = a / tot;
    }
    __syncthreads();

    // projection: 512 threads; (ii, o, q) sums 16 d's
    {
        const int ii = t >> 8, rem = t & 255;
        const int o = rem & 63, q = rem >> 6;
        float v = 0.0f;
        #pragma unroll
        for (int d4 = 0; d4 < 4; ++d4) {
            const int d = q * 16 + d4 * 4;
            const float4 w1 = *(const float4*)(W1 + o * DD + d);
            const float4 w2 = *(const float4*)(W2 + o * DD + d);
            const float4 ag = *(const float4*)(&s_agg[ii][d]);   // broadcast
            const float4 xi = *(const float4*)(&s_xi[ii][d]);    // broadcast
            v = fmaf(w1.x, ag.x, fmaf(w2.x, xi.x, v));
            v = fmaf(w1.y, ag.y, fmaf(w2.y, xi.y, v));
            v = fmaf(w1.z, ag.z, fmaf(w2.z, xi.z, v));
            v = fmaf(w1.w, ag.w, fmaf(w2.w, xi.w, v));
        }
        part[ii][q][o] = v;
    }
    __syncthreads();
    if (t < 128) {
        const int ii = t >> 6, o = t & 63;
        const float v = b1[o] + b2[o]
            + ((part[ii][0][o] + part[ii][1][o]) + (part[ii][2][o] + part[ii][3][o]));
        out[((size_t)(blk * 2 + ii)) * DD + o] = v;    // row = b*512 + i0 + ii
        atomicAdd(&stats[o], v);
        atomicAdd(&stats[64 + o], v * v);
    }
}

// BN (batch stats, biased var) + selu, IN PLACE on out; float4 I/O.
__global__ __launch_bounds__(256) void final_kernel(
    const float* __restrict__ stats,
    const float* __restrict__ gamma, const float* __restrict__ beta,
    float* __restrict__ out)
{
    __shared__ float smu[DD], sga[DD], sbe[DD];
    if (threadIdx.x < DD) {
        const int o = threadIdx.x;
        const float mean = stats[o] * (1.0f / BN_ROWS);
        const float var  = stats[64 + o] * (1.0f / BN_ROWS) - mean * mean;
        smu[o] = mean;
        sga[o] = gamma[o] / sqrtf(var + 1e-5f);
        sbe[o] = beta[o];
    }
    __syncthreads();
    const int i4 = blockIdx.x * 256 + threadIdx.x;   // grid 512 -> exactly 131072
    const int o0 = (i4 & 15) * 4;
    const float4 v = ((const float4*)out)[i4];
    float r[4] = { v.x, v.y, v.z, v.w };
    #pragma unroll
    for (int c = 0; c < 4; ++c) {
        const float nrm = (r[c] - smu[o0 + c]) * sga[o0 + c] + sbe[o0 + c];
        r[c] = nrm > 0.0f
            ? 1.0507009873554805f * nrm
            : 1.7580993408473766f * expm1f(nrm);
    }
    ((float4*)out)[i4] = make_float4(r[0], r[1], r[2], r[3]);
}

extern "C" void kernel_launch(void* const* d_in, const int* in_sizes, int n_in,
                              void* d_out, int out_size, void* d_ws, size_t ws_size,
                              hipStream_t stream)
{
    const float* x  = (const float*)d_in[0];
    const float* Wp = (const float*)d_in[1];  // W_att_proj
    const float* bp = (const float*)d_in[2];  // b_att_proj
    const float* aw = (const float*)d_in[3];  // att_weight
    const float* W1 = (const float*)d_in[4];  // W_with
    const float* b1 = (const float*)d_in[5];  // b_with
    const float* W2 = (const float*)d_in[6];  // W_without
    const float* b2 = (const float*)d_in[7];  // b_without
    const float* ga = (const float*)d_in[8];  // gamma
    const float* be = (const float*)d_in[9];  // beta

    float*  stats = (float*)d_ws;                       // 128 floats
    float*  wpf   = stats + 128;                        // 4096 fp32 (A-frag order)
    ushort* xbf   = (ushort*)(wpf + DD * DD);           // 524288 bf16 (B-frag order)
    float*  out   = (float*)d_out;                      // fp32 output

    prep_kernel<<<256, 256, 0, stream>>>(x, Wp, wpf, xbf, stats);
    attn_kernel<<<BN_ROWS / 2, 512, 0, stream>>>(x, wpf, xbf, bp, aw, W1, b1, W2, b2, out, stats);
    final_kernel<<<512, 256, 0, stream>>>(stats, ga, be, out);
}

// Round 25
// 284.436 us; speedup vs baseline: 1.0298x; 1.0298x over previous
//
#include <hip/hip_runtime.h>
#include <hip/hip_bf16.h>

#define BB 16
#define NN 512
#define DD 64
#define BN_ROWS (BB * NN)   // 8192

typedef unsigned short ushort;
typedef unsigned int uint;
typedef short bf16x8 __attribute__((ext_vector_type(8)));   // 8 bf16 = 4 VGPRs
typedef float f32x4  __attribute__((ext_vector_type(4)));   // MFMA acc

// ws layout: stats[128] | wpf fp32 frag-ordered [4096] | xbf bf16 frag-ordered [524288]
// Identities: Wp·(xi⊙xj) = (Wp⊙xi)·xj ; agg = (Σ e_j·x_j)/(Σ e_j), fused pass.
// R25: XCD-aware swizzle — blocks with blk%8==x all handle b∈{2x,2x+1}, so each
// XCD's xbf working set is 128 KB (guaranteed L2-resident). Otherwise exact R23.

__device__ __forceinline__ uint pkbf2(float lo, float hi) {
    union { float f; uint u; } a, b; a.f = lo; b.f = hi;
    return __builtin_amdgcn_perm(b.u + 0x8000u, a.u + 0x8000u, 0x07060302u);
}
__device__ __forceinline__ float bflo(uint u) {
    union { uint i; float f; } c; c.i = u << 16; return c.f;
}
__device__ __forceinline__ float bfhi(uint u) {
    union { uint i; float f; } c; c.i = u & 0xffff0000u; return c.f;
}

// no clamp: e=inf -> rcp=0 -> 1 (correct limit); e=0 -> -1 (correct)
__device__ __forceinline__ float fast_tanh(float x) {
    const float e = __builtin_amdgcn_exp2f(x * 2.885390081777927f); // 2x*log2(e)
    return 1.0f - 2.0f * __builtin_amdgcn_rcpf(e + 1.0f);
}

// One-time: x -> bf16 B-frag order; Wp -> fp32 A-frag order; zero stats.
__global__ __launch_bounds__(256) void prep_kernel(
    const float* __restrict__ x, const float* __restrict__ Wp,
    float* __restrict__ wpf, ushort* __restrict__ xbf, float* __restrict__ stats)
{
    const int tid = blockIdx.x * 256 + threadIdx.x;     // grid 256 -> 0..65535
    const int b = tid >> 12, rem = tid & 4095;
    const int jt = rem >> 7, ks = (rem >> 6) & 1, lane = rem & 63;
    const int qd = lane >> 4, ln = lane & 15;
    const float* __restrict__ src =
        x + ((size_t)(b * NN + jt * 16 + ln)) * DD + ks * 32 + qd * 8;
    const float4 v0 = *(const float4*)src;
    const float4 v1 = *(const float4*)(src + 4);
    uint4 o;
    o.x = pkbf2(v0.x, v0.y); o.y = pkbf2(v0.z, v0.w);
    o.z = pkbf2(v1.x, v1.y); o.w = pkbf2(v1.z, v1.w);
    ((uint4*)xbf)[tid] = o;                              // coalesced
    if (tid < DD * DD) {
        const int oo = tid >> 6, d = tid & 63;
        const int mt = oo >> 4, l2 = oo & 15;
        const int k2 = d >> 5, q2 = (d >> 3) & 3, e = d & 7;
        wpf[(((mt * 2 + k2) * 64) + (q2 * 16 + l2)) * 8 + e] = Wp[tid];
    }
    if (tid < 128) stats[tid] = 0.0f;
}

// One block (512 thr, 8 waves) per (b,i); wave wv owns j-tiles wv*4..wv*4+3.
// Fused score+aggregate per wave; block-reduce (esum, vacc); project.
// XCD swizzle: b = (blk&7)*2 + ((blk>>3)&1), i = blk>>4 (bijective over 8192).
__global__ __launch_bounds__(512, 3) void attn_kernel(
    const float* __restrict__ x,  const float* __restrict__ wpf,
    const ushort* __restrict__ xbf,
    const float* __restrict__ bp, const float* __restrict__ aw,
    const float* __restrict__ W1, const float* __restrict__ b1,
    const float* __restrict__ W2, const float* __restrict__ b2,
    float* __restrict__ out, float* __restrict__ stats)
{
    __shared__ float part[8][DD];                   // 2 KB (reused twice)
    __shared__ __align__(16) float s_xi[DD], s_agg[DD], s_bp[DD], s_aw[DD];
    __shared__ float s_esum[8];

    const int t = threadIdx.x;                      // 0..511
    const int wv = t >> 6, lane = t & 63;
    const int blk = blockIdx.x;                     // 0..8191
    const int b = (blk & 7) * 2 + ((blk >> 3) & 1); // XCD-local b
    const int i = blk >> 4;                         // 0..511
    const int row = b * NN + i;                     // output row index
    const int qd = lane >> 4, ln = lane & 15;
    const ushort* __restrict__ xb16 = xbf + (size_t)b * (NN * DD);

    if (t < DD) {
        s_bp[t] = bp[t];
        s_aw[t] = aw[t];
        s_xi[t] = x[(size_t)row * DD + t];
    }
    __syncthreads();

    float xiv[2][8];
    #pragma unroll
    for (int ks = 0; ks < 2; ++ks) {
        const float4 a = *(const float4*)(s_xi + ks * 32 + qd * 8);
        const float4 c = *(const float4*)(s_xi + ks * 32 + qd * 8 + 4);
        xiv[ks][0]=a.x; xiv[ks][1]=a.y; xiv[ks][2]=a.z; xiv[ks][3]=a.w;
        xiv[ks][4]=c.x; xiv[ks][5]=c.y; xiv[ks][6]=c.z; xiv[ks][7]=c.w;
    }

    // A-frags: Wp⊙xi in bf16, g = mt*2+ks (each wave builds its own copy)
    bf16x8 afrag[8];
    #pragma unroll
    for (int g = 0; g < 8; ++g) {
        const int ks = g & 1;
        const float4 wa = *(const float4*)(wpf + (g * 64 + lane) * 8);
        const float4 wb = *(const float4*)(wpf + (g * 64 + lane) * 8 + 4);
        union { bf16x8 v; uint u[4]; } p;
        p.u[0] = pkbf2(wa.x * xiv[ks][0], wa.y * xiv[ks][1]);
        p.u[1] = pkbf2(wa.z * xiv[ks][2], wa.w * xiv[ks][3]);
        p.u[2] = pkbf2(wb.x * xiv[ks][4], wb.y * xiv[ks][5]);
        p.u[3] = pkbf2(wb.z * xiv[ks][6], wb.w * xiv[ks][7]);
        afrag[g] = p.v;
    }

    float bpv[16], awv[16];
    #pragma unroll
    for (int mt = 0; mt < 4; ++mt)
        #pragma unroll
        for (int r = 0; r < 4; ++r) {
            bpv[mt * 4 + r] = s_bp[mt * 16 + qd * 4 + r];
            awv[mt * 4 + r] = s_aw[mt * 16 + qd * 4 + r];
        }

    // ---- FUSED score + aggregate: 4 j-tiles for this wave ----
    float vacc[16];
    #pragma unroll
    for (int k = 0; k < 16; ++k) vacc[k] = 0.0f;
    float esum = 0.0f;

    #pragma unroll
    for (int tt = 0; tt < 4; ++tt) {
        const int tile = wv * 4 + tt;
        union { bf16x8 v; uint4 u; } b0, b1u;
        b0.v  = *(const bf16x8*)(xb16 + ((tile * 2 + 0) * 64 + lane) * 8);
        b1u.v = *(const bf16x8*)(xb16 + ((tile * 2 + 1) * 64 + lane) * 8);

        float s0 = 0.0f, s1 = 0.0f, s2 = 0.0f, s3 = 0.0f;
        #pragma unroll
        for (int mt = 0; mt < 4; ++mt) {
            f32x4 acc = { bpv[mt*4+0], bpv[mt*4+1], bpv[mt*4+2], bpv[mt*4+3] };
            acc = __builtin_amdgcn_mfma_f32_16x16x32_bf16(afrag[mt*2+0], b0.v,  acc, 0, 0, 0);
            acc = __builtin_amdgcn_mfma_f32_16x16x32_bf16(afrag[mt*2+1], b1u.v, acc, 0, 0, 0);
            s0 = fmaf(awv[mt*4+0], fast_tanh(acc[0]), s0);
            s1 = fmaf(awv[mt*4+1], fast_tanh(acc[1]), s1);
            s2 = fmaf(awv[mt*4+2], fast_tanh(acc[2]), s2);
            s3 = fmaf(awv[mt*4+3], fast_tanh(acc[3]), s3);
        }
        float sj = (s0 + s1) + (s2 + s3);
        sj += __shfl_xor(sj, 16);
        sj += __shfl_xor(sj, 32);        // all quads: s for j = tile*16 + ln

        const float e = __builtin_amdgcn_exp2f(sj * 1.4426950408889634f);
        esum += e;
        vacc[0]  = fmaf(e, bflo(b0.u.x),  vacc[0]);
        vacc[1]  = fmaf(e, bfhi(b0.u.x),  vacc[1]);
        vacc[2]  = fmaf(e, bflo(b0.u.y),  vacc[2]);
        vacc[3]  = fmaf(e, bfhi(b0.u.y),  vacc[3]);
        vacc[4]  = fmaf(e, bflo(b0.u.z),  vacc[4]);
        vacc[5]  = fmaf(e, bfhi(b0.u.z),  vacc[5]);
        vacc[6]  = fmaf(e, bflo(b0.u.w),  vacc[6]);
        vacc[7]  = fmaf(e, bfhi(b0.u.w),  vacc[7]);
        vacc[8]  = fmaf(e, bflo(b1u.u.x), vacc[8]);
        vacc[9]  = fmaf(e, bfhi(b1u.u.x), vacc[9]);
        vacc[10] = fmaf(e, bflo(b1u.u.y), vacc[10]);
        vacc[11] = fmaf(e, bfhi(b1u.u.y), vacc[11]);
        vacc[12] = fmaf(e, bflo(b1u.u.z), vacc[12]);
        vacc[13] = fmaf(e, bfhi(b1u.u.z), vacc[13]);
        vacc[14] = fmaf(e, bflo(b1u.u.w), vacc[14]);
        vacc[15] = fmaf(e, bfhi(b1u.u.w), vacc[15]);
    }

    // reduce over ln within wave (each quad holds identical esum copies)
    #pragma unroll
    for (int off = 1; off < 16; off <<= 1) {
        esum += __shfl_xor(esum, off);
        #pragma unroll
        for (int k = 0; k < 16; ++k)
            vacc[k] += __shfl_xor(vacc[k], off);
    }
    if (lane == 0) s_esum[wv] = esum;
    if (ln == 0) {
        #pragma unroll
        for (int k = 0; k < 16; ++k)
            part[wv][(k >> 3) * 32 + qd * 8 + (k & 7)] = vacc[k];
    }
    __syncthreads();

    // block combine: agg[d] = (Σ_wv part[wv][d]) / (Σ_wv esum[wv])
    if (t < DD) {
        const float tot = ((s_esum[0] + s_esum[1]) + (s_esum[2] + s_esum[3]))
                        + ((s_esum[4] + s_esum[5]) + (s_esum[6] + s_esum[7]));
        const float inv = 1.0f / tot;
        const float a = ((part[0][t] + part[1][t]) + (part[2][t] + part[3][t]))
                      + ((part[4][t] + part[5][t]) + (part[6][t] + part[7][t]));
        s_agg[t] = a * inv;
    }
    __syncthreads();

    // projection: 512 threads; thread (o, q) sums 8 d's
    {
        const int o = t & 63, q = t >> 6;
        const float4 w1a = *(const float4*)(W1 + o * DD + q * 8);
        const float4 w1b = *(const float4*)(W1 + o * DD + q * 8 + 4);
        const float4 w2a = *(const float4*)(W2 + o * DD + q * 8);
        const float4 w2b = *(const float4*)(W2 + o * DD + q * 8 + 4);
        const float4 aga = *(const float4*)(s_agg + q * 8);
        const float4 agb = *(const float4*)(s_agg + q * 8 + 4);
        const float4 xia = *(const float4*)(s_xi + q * 8);
        const float4 xib = *(const float4*)(s_xi + q * 8 + 4);
        float v = 0.0f;
        v = fmaf(w1a.x, aga.x, fmaf(w2a.x, xia.x, v));
        v = fmaf(w1a.y, aga.y, fmaf(w2a.y, xia.y, v));
        v = fmaf(w1a.z, aga.z, fmaf(w2a.z, xia.z, v));
        v = fmaf(w1a.w, aga.w, fmaf(w2a.w, xia.w, v));
        v = fmaf(w1b.x, agb.x, fmaf(w2b.x, xib.x, v));
        v = fmaf(w1b.y, agb.y, fmaf(w2b.y, xib.y, v));
        v = fmaf(w1b.z, agb.z, fmaf(w2b.z, xib.z, v));
        v = fmaf(w1b.w, agb.w, fmaf(w2b.w, xib.w, v));
        part[q][o] = v;
    }
    __syncthreads();
    if (t < DD) {
        const int o = t;
        const float v = b1[o] + b2[o]
            + ((part[0][o] + part[1][o]) + (part[2][o] + part[3][o]))
            + ((part[4][o] + part[5][o]) + (part[6][o] + part[7][o]));
        out[(size_t)row * DD + o] = v;     // pre-BN x_out into d_out
        atomicAdd(&stats[o], v);
        atomicAdd(&stats[64 + o], v * v);
    }
}

// BN (batch stats, biased var) + selu, IN PLACE on out; float4 I/O.
__global__ __launch_bounds__(256) void final_kernel(
    const float* __restrict__ stats,
    const float* __restrict__ gamma, const float* __restrict__ beta,
    float* __restrict__ out)
{
    __shared__ float smu[DD], sga[DD], sbe[DD];
    if (threadIdx.x < DD) {
        const int o = threadIdx.x;
        const float mean = stats[o] * (1.0f / BN_ROWS);
        const float var  = stats[64 + o] * (1.0f / BN_ROWS) - mean * mean;
        smu[o] = mean;
        sga[o] = gamma[o] / sqrtf(var + 1e-5f);
        sbe[o] = beta[o];
    }
    __syncthreads();
    const int i4 = blockIdx.x * 256 + threadIdx.x;   // grid 512 -> exactly 131072
    const int o0 = (i4 & 15) * 4;
    const float4 v = ((const float4*)out)[i4];
    float r[4] = { v.x, v.y, v.z, v.w };
    #pragma unroll
    for (int c = 0; c < 4; ++c) {
        const float nrm = (r[c] - smu[o0 + c]) * sga[o0 + c] + sbe[o0 + c];
        r[c] = nrm > 0.0f
            ? 1.0507009873554805f * nrm
            : 1.7580993408473766f * expm1f(nrm);
    }
    ((float4*)out)[i4] = make_float4(r[0], r[1], r[2], r[3]);
}

extern "C" void kernel_launch(void* const* d_in, const int* in_sizes, int n_in,
                              void* d_out, int out_size, void* d_ws, size_t ws_size,
                              hipStream_t stream)
{
    const float* x  = (const float*)d_in[0];
    const float* Wp = (const float*)d_in[1];  // W_att_proj
    const float* bp = (const float*)d_in[2];  // b_att_proj
    const float* aw = (const float*)d_in[3];  // att_weight
    const float* W1 = (const float*)d_in[4];  // W_with
    const float* b1 = (const float*)d_in[5];  // b_with
    const float* W2 = (const float*)d_in[6];  // W_without
    const float* b2 = (const float*)d_in[7];  // b_without
    const float* ga = (const float*)d_in[8];  // gamma
    const float* be = (const float*)d_in[9];  // beta

    float*  stats = (float*)d_ws;                       // 128 floats
    float*  wpf   = stats + 128;                        // 4096 fp32 (A-frag order)
    ushort* xbf   = (ushort*)(wpf + DD * DD);           // 524288 bf16 (B-frag order)
    float*  out   = (float*)d_out;                      // fp32 output

    prep_kernel<<<256, 256, 0, stream>>>(x, Wp, wpf, xbf, stats);
    attn_kernel<<<BN_ROWS, 512, 0, stream>>>(x, wpf, xbf, bp, aw, W1, b1, W2, b2, out, stats);
    final_kernel<<<512, 256, 0, stream>>>(stats, ga, be, out);
}